// Round 1
// baseline (349.605 us; speedup 1.0000x reference)
//
#include <hip/hip_runtime.h>

// ---------- types ----------
typedef __attribute__((ext_vector_type(8))) short short8;    // 8 bf16 (4 VGPRs)
typedef __attribute__((ext_vector_type(4))) float floatx4;   // MFMA acc

// fp32 -> bf16 (RNE)
static __device__ __forceinline__ unsigned short f2bf(float f) {
    unsigned int u = __float_as_uint(f);
    u = (u + 0x7FFFu + ((u >> 16) & 1u)) >> 16;
    return (unsigned short)u;
}

// ---------- kernel 1: W (256x512 f32) -> Wt (512x256 bf16) ----------
__global__ void prep_wt_kernel(const float* __restrict__ W,
                               unsigned short* __restrict__ Wt) {
    int g = blockIdx.x * blockDim.x + threadIdx.x;   // 0 .. 512*256-1
    int n = g >> 8;          // 0..511
    int k = g & 255;         // 0..255
    Wt[g] = f2bf(W[k * 512 + n]);
}

// ---------- kernel 2: segment mean -> cell_emb bf16 [Mpad][256] ----------
// one wave per cell; segment_ids sorted -> binary search the range
__global__ void seg_mean_kernel(const float* __restrict__ chunk_features,
                                const int* __restrict__ member_idx,
                                const int* __restrict__ segment_ids,
                                int M,
                                unsigned short* __restrict__ cell_emb) {
    const int wid  = threadIdx.x >> 6;
    const int lane = threadIdx.x & 63;
    const int c = blockIdx.x * 4 + wid;

    // lower_bound(c)
    int lo = 0, hi = M;
    while (lo < hi) { int mid = (lo + hi) >> 1; if (segment_ids[mid] < c) lo = mid + 1; else hi = mid; }
    const int s = lo;
    // lower_bound(c+1)
    hi = M;
    while (lo < hi) { int mid = (lo + hi) >> 1; if (segment_ids[mid] < c + 1) lo = mid + 1; else hi = mid; }
    const int e = lo;

    float4 acc = make_float4(0.f, 0.f, 0.f, 0.f);
    const float4* cf = (const float4*)chunk_features;   // rows of 64 float4

    for (int base = s; base < e; base += 64) {
        int m = base + lane;
        int idx = (m < e) ? member_idx[m] : 0;
        int n = e - base; if (n > 64) n = 64;
        for (int j = 0; j < n; ++j) {
            int ci = __shfl(idx, j);
            float4 v = cf[(size_t)ci * 64 + lane];
            acc.x += v.x; acc.y += v.y; acc.z += v.z; acc.w += v.w;
        }
    }

    int cnt = e - s;
    float inv = 1.0f / (float)(cnt > 0 ? cnt : 1);
    ushort4 o;
    o.x = f2bf(acc.x * inv);
    o.y = f2bf(acc.y * inv);
    o.z = f2bf(acc.z * inv);
    o.w = f2bf(acc.w * inv);
    *(ushort4*)(cell_emb + (size_t)c * 256 + lane * 4) = o;
}

// ---------- kernel 3: C[Mpad x 512] = A[Mpad x 256] * W[256 x 512] + b ----------
// A bf16 row-major, Bt = W^T bf16 row-major [512][256].
// 128x128 block tile, 4 waves (2x2), 64x64 wave tile, BK=32, 16x16x32 MFMA.
__global__ __launch_bounds__(256) void gemm_kernel(
        const unsigned short* __restrict__ A,
        const unsigned short* __restrict__ Bt,
        const float* __restrict__ bias,
        float* __restrict__ out,
        int Mreal) {
    constexpr int LDSS = 40;             // padded stride (bf16 elems) to spread banks
    __shared__ unsigned short As[128 * LDSS];
    __shared__ unsigned short Bs[128 * LDSS];

    const int tid  = threadIdx.x;
    const int wid  = tid >> 6;
    const int lane = tid & 63;
    const int wm = wid & 1, wn = wid >> 1;
    const int l15 = lane & 15, q = lane >> 4;
    const int m0 = blockIdx.y * 128;
    const int n0 = blockIdx.x * 128;

    floatx4 acc[4][4] = {};

    for (int kb = 0; kb < 256; kb += 32) {
        // stage 128x32 A-tile and 128x32 Bt-tile (8 KB each), 16B per load
#pragma unroll
        for (int r = 0; r < 2; ++r) {
            int chunk = tid + r * 256;          // 0..511
            int row = chunk >> 2;               // 0..127
            int col = (chunk & 3) * 8;          // 0,8,16,24
            *(short8*)&As[row * LDSS + col] =
                *(const short8*)&A[(size_t)(m0 + row) * 256 + kb + col];
            *(short8*)&Bs[row * LDSS + col] =
                *(const short8*)&Bt[(size_t)(n0 + row) * 256 + kb + col];
        }
        __syncthreads();

        short8 af[4], bf[4];
#pragma unroll
        for (int mi = 0; mi < 4; ++mi)
            af[mi] = *(const short8*)&As[(wm * 64 + mi * 16 + l15) * LDSS + q * 8];
#pragma unroll
        for (int ni = 0; ni < 4; ++ni)
            bf[ni] = *(const short8*)&Bs[(wn * 64 + ni * 16 + l15) * LDSS + q * 8];
#pragma unroll
        for (int mi = 0; mi < 4; ++mi)
#pragma unroll
            for (int ni = 0; ni < 4; ++ni)
                acc[mi][ni] = __builtin_amdgcn_mfma_f32_16x16x32_bf16(
                    af[mi], bf[ni], acc[mi][ni], 0, 0, 0);
        __syncthreads();
    }

    // epilogue: C[row][n] = acc + bias[n]; C/D layout col=lane&15, row=q*4+reg
#pragma unroll
    for (int ni = 0; ni < 4; ++ni) {
        int n = n0 + wn * 64 + ni * 16 + l15;
        float bv = bias[n];
#pragma unroll
        for (int mi = 0; mi < 4; ++mi) {
            int mbase = m0 + wm * 64 + mi * 16 + q * 4;
#pragma unroll
            for (int r = 0; r < 4; ++r) {
                int row = mbase + r;
                if (row < Mreal)
                    out[(size_t)row * 512 + n] = acc[mi][ni][r] + bv;
            }
        }
    }
}

extern "C" void kernel_launch(void* const* d_in, const int* in_sizes, int n_in,
                              void* d_out, int out_size, void* d_ws, size_t ws_size,
                              hipStream_t stream) {
    const float* chunk_features = (const float*)d_in[0];
    const int*   member_idx     = (const int*)d_in[1];
    const int*   segment_ids    = (const int*)d_in[2];
    // d_in[3] = num_cells scalar on device (value derived from out_size instead)
    const float* W              = (const float*)d_in[4];
    const float* bias           = (const float*)d_in[5];
    float* out = (float*)d_out;

    const int M        = in_sizes[1];            // 400000 members
    const int out_dim  = in_sizes[5];            // 512
    const int num_cells = out_size / out_dim;    // 50000
    const int mtiles = (num_cells + 127) / 128;  // 391
    const int Mpad   = mtiles * 128;             // 50048

    unsigned short* cell_emb = (unsigned short*)d_ws;                 // Mpad*256 bf16
    unsigned short* Wt       = cell_emb + (size_t)Mpad * 256;         // 512*256 bf16

    hipLaunchKernelGGL(prep_wt_kernel, dim3(512), dim3(256), 0, stream, W, Wt);
    hipLaunchKernelGGL(seg_mean_kernel, dim3(Mpad / 4), dim3(256), 0, stream,
                       chunk_features, member_idx, segment_ids, M, cell_emb);
    hipLaunchKernelGGL(gemm_kernel, dim3(4, mtiles), dim3(256), 0, stream,
                       cell_emb, Wt, bias, out, num_cells);
}

// Round 2
// 282.201 us; speedup vs baseline: 1.2389x; 1.2389x over previous
//
#include <hip/hip_runtime.h>

// ---------- types ----------
typedef __attribute__((ext_vector_type(8))) short short8;    // 8 bf16 (4 VGPRs)
typedef __attribute__((ext_vector_type(4))) float floatx4;   // MFMA acc

// fp32 -> bf16 (RNE)
static __device__ __forceinline__ unsigned short f2bf(float f) {
    unsigned int u = __float_as_uint(f);
    u = (u + 0x7FFFu + ((u >> 16) & 1u)) >> 16;
    return (unsigned short)u;
}

// ---------- kernel 0: starts[c] = lower_bound(segment_ids, c), c in [0, num_cells] ----------
// segment_ids sorted. Thread m writes starts[c] = m for all c in (seg[m-1], seg[m]].
// Thread M handles the tail (seg[M-1], num_cells]. Every c written exactly once.
__global__ void starts_kernel(const int* __restrict__ seg, int M, int num_cells,
                              int* __restrict__ starts) {
    int m = blockIdx.x * blockDim.x + threadIdx.x;
    if (m > M) return;
    int prev = (m == 0) ? -1 : seg[m - 1];
    int cur  = (m == M) ? num_cells : seg[m];
    for (int c = prev + 1; c <= cur; ++c) starts[c] = m;
}

// ---------- kernel 1: W (256x512 f32) -> Wt (512x256 bf16) ----------
__global__ void prep_wt_kernel(const float* __restrict__ W,
                               unsigned short* __restrict__ Wt) {
    int g = blockIdx.x * blockDim.x + threadIdx.x;   // 0 .. 512*256-1
    int n = g >> 8;          // 0..511
    int k = g & 255;         // 0..255
    Wt[g] = f2bf(W[k * 512 + n]);
}

// ---------- kernel 2: segment mean -> cell_emb bf16 [Mpad][256] ----------
// one wave per cell; range comes from precomputed starts[] (no binary search)
__global__ void seg_mean_kernel(const float* __restrict__ chunk_features,
                                const int* __restrict__ member_idx,
                                const int* __restrict__ starts,
                                int num_cells,
                                unsigned short* __restrict__ cell_emb) {
    const int wid  = threadIdx.x >> 6;
    const int lane = threadIdx.x & 63;
    const int c = blockIdx.x * 4 + wid;

    float4 acc = make_float4(0.f, 0.f, 0.f, 0.f);
    int cnt = 0;

    if (c < num_cells) {
        const int s = starts[c];
        const int e = starts[c + 1];
        cnt = e - s;
        const float4* cf = (const float4*)chunk_features;   // rows of 64 float4

        for (int base = s; base < e; base += 64) {
            int m = base + lane;
            int idx = (m < e) ? member_idx[m] : 0;
            int n = e - base; if (n > 64) n = 64;
            // depth-2 pipeline: next row load in flight while accumulating current
            int ci = __shfl(idx, 0);
            float4 vn = cf[(size_t)ci * 64 + lane];
            for (int j = 0; j < n - 1; ++j) {
                float4 v = vn;
                int cin = __shfl(idx, j + 1);
                vn = cf[(size_t)cin * 64 + lane];
                acc.x += v.x; acc.y += v.y; acc.z += v.z; acc.w += v.w;
            }
            acc.x += vn.x; acc.y += vn.y; acc.z += vn.z; acc.w += vn.w;
        }
    }

    float inv = 1.0f / (float)(cnt > 0 ? cnt : 1);
    ushort4 o;
    o.x = f2bf(acc.x * inv);
    o.y = f2bf(acc.y * inv);
    o.z = f2bf(acc.z * inv);
    o.w = f2bf(acc.w * inv);
    *(ushort4*)(cell_emb + (size_t)c * 256 + lane * 4) = o;
}

// ---------- kernel 3: C[Mpad x 512] = A[Mpad x 256] * W[256 x 512] + b ----------
// A bf16 row-major, Bt = W^T bf16 row-major [512][256].
// 128x128 block tile, 4 waves (2x2), 64x64 wave tile, BK=32, 16x16x32 MFMA.
__global__ __launch_bounds__(256) void gemm_kernel(
        const unsigned short* __restrict__ A,
        const unsigned short* __restrict__ Bt,
        const float* __restrict__ bias,
        float* __restrict__ out,
        int Mreal) {
    constexpr int LDSS = 40;             // padded stride (bf16 elems) to spread banks
    __shared__ unsigned short As[128 * LDSS];
    __shared__ unsigned short Bs[128 * LDSS];

    const int tid  = threadIdx.x;
    const int wid  = tid >> 6;
    const int lane = tid & 63;
    const int wm = wid & 1, wn = wid >> 1;
    const int l15 = lane & 15, q = lane >> 4;
    const int m0 = blockIdx.y * 128;
    const int n0 = blockIdx.x * 128;

    floatx4 acc[4][4] = {};

    for (int kb = 0; kb < 256; kb += 32) {
        // stage 128x32 A-tile and 128x32 Bt-tile (8 KB each), 16B per load
#pragma unroll
        for (int r = 0; r < 2; ++r) {
            int chunk = tid + r * 256;          // 0..511
            int row = chunk >> 2;               // 0..127
            int col = (chunk & 3) * 8;          // 0,8,16,24
            *(short8*)&As[row * LDSS + col] =
                *(const short8*)&A[(size_t)(m0 + row) * 256 + kb + col];
            *(short8*)&Bs[row * LDSS + col] =
                *(const short8*)&Bt[(size_t)(n0 + row) * 256 + kb + col];
        }
        __syncthreads();

        short8 af[4], bf[4];
#pragma unroll
        for (int mi = 0; mi < 4; ++mi)
            af[mi] = *(const short8*)&As[(wm * 64 + mi * 16 + l15) * LDSS + q * 8];
#pragma unroll
        for (int ni = 0; ni < 4; ++ni)
            bf[ni] = *(const short8*)&Bs[(wn * 64 + ni * 16 + l15) * LDSS + q * 8];
#pragma unroll
        for (int mi = 0; mi < 4; ++mi)
#pragma unroll
            for (int ni = 0; ni < 4; ++ni)
                acc[mi][ni] = __builtin_amdgcn_mfma_f32_16x16x32_bf16(
                    af[mi], bf[ni], acc[mi][ni], 0, 0, 0);
        __syncthreads();
    }

    // epilogue: C[row][n] = acc + bias[n]; C/D layout col=lane&15, row=q*4+reg
#pragma unroll
    for (int ni = 0; ni < 4; ++ni) {
        int n = n0 + wn * 64 + ni * 16 + l15;
        float bv = bias[n];
#pragma unroll
        for (int mi = 0; mi < 4; ++mi) {
            int mbase = m0 + wm * 64 + mi * 16 + q * 4;
#pragma unroll
            for (int r = 0; r < 4; ++r) {
                int row = mbase + r;
                if (row < Mreal)
                    out[(size_t)row * 512 + n] = acc[mi][ni][r] + bv;
            }
        }
    }
}

extern "C" void kernel_launch(void* const* d_in, const int* in_sizes, int n_in,
                              void* d_out, int out_size, void* d_ws, size_t ws_size,
                              hipStream_t stream) {
    const float* chunk_features = (const float*)d_in[0];
    const int*   member_idx     = (const int*)d_in[1];
    const int*   segment_ids    = (const int*)d_in[2];
    // d_in[3] = num_cells scalar on device (value derived from out_size instead)
    const float* W              = (const float*)d_in[4];
    const float* bias           = (const float*)d_in[5];
    float* out = (float*)d_out;

    const int M        = in_sizes[1];            // 400000 members
    const int out_dim  = in_sizes[5];            // 512
    const int num_cells = out_size / out_dim;    // 50000
    const int mtiles = (num_cells + 127) / 128;  // 391
    const int Mpad   = mtiles * 128;             // 50048

    unsigned short* cell_emb = (unsigned short*)d_ws;                 // Mpad*256 bf16
    unsigned short* Wt       = cell_emb + (size_t)Mpad * 256;         // 512*256 bf16
    int*            starts   = (int*)(Wt + 512 * 256);                // num_cells+1 ints

    hipLaunchKernelGGL(starts_kernel, dim3((M + 1 + 255) / 256), dim3(256), 0, stream,
                       segment_ids, M, num_cells, starts);
    hipLaunchKernelGGL(prep_wt_kernel, dim3(512), dim3(256), 0, stream, W, Wt);
    hipLaunchKernelGGL(seg_mean_kernel, dim3(Mpad / 4), dim3(256), 0, stream,
                       chunk_features, member_idx, starts, num_cells, cell_emb);
    hipLaunchKernelGGL(gemm_kernel, dim3(4, mtiles), dim3(256), 0, stream,
                       cell_emb, Wt, bias, out, num_cells);
}